// Round 6
// baseline (2743.298 us; speedup 1.0000x reference)
//
#include <hip/hip_runtime.h>

// Problem constants (fixed by reference)
#define HH   480
#define WW   640
#define HWP  (HH*WW)      // 307200
#define NSEM 12
#define NINS 16
#define NCH  28           // sem channels then ins channels

// ---------------------------------------------------------------------------
// bf16 helpers (raw ushort storage, RNE rounding)
// ---------------------------------------------------------------------------
__device__ __forceinline__ float bf2f(unsigned short u) {
    return __uint_as_float(((unsigned int)u) << 16);
}
__device__ __forceinline__ unsigned short f2bf(float f) {
    unsigned int b = __float_as_uint(f);
    return (unsigned short)((b + 0x7FFFu + ((b >> 16) & 1u)) >> 16);
}

// 13-tap Gaussian (sigma=3, r=6)
__device__ __forceinline__ void gauss13(float k[13]) {
    float s = 0.f;
#pragma unroll
    for (int j = 0; j < 13; ++j) {
        float xx = (float)(j - 6);
        float v  = __expf(-(xx * xx) * (1.f / 18.f));
        k[j] = v; s += v;
    }
    float inv = 1.f / s;
#pragma unroll
    for (int j = 0; j < 13; ++j) k[j] *= inv;
}

template <int N>
__device__ __forceinline__ void softmaxN(const float* __restrict__ in, float* __restrict__ out) {
    float m = in[0];
#pragma unroll
    for (int i = 1; i < N; ++i) m = fmaxf(m, in[i]);
    float s = 0.f;
#pragma unroll
    for (int i = 0; i < N; ++i) { float e = __expf(in[i] - m); out[i] = e; s += e; }
    float inv = 1.f / s;
#pragma unroll
    for (int i = 0; i < N; ++i) out[i] *= inv;
}

// ---------------------------------------------------------------------------
// Init: softmax(logits) -> q (bf16)
// ---------------------------------------------------------------------------
__global__ __launch_bounds__(256) void init_kernel(const float* __restrict__ semL,
                                                   const float* __restrict__ insL,
                                                   unsigned short* __restrict__ q) {
    int p = blockIdx.x * 256 + threadIdx.x;
    float v[NINS], o[NINS];
#pragma unroll
    for (int i = 0; i < NSEM; ++i) v[i] = semL[i * HWP + p];
    softmaxN<NSEM>(v, o);
#pragma unroll
    for (int i = 0; i < NSEM; ++i) q[i * HWP + p] = f2bf(o[i]);
#pragma unroll
    for (int i = 0; i < NINS; ++i) v[i] = insL[i * HWP + p];
    softmaxN<NINS>(v, o);
#pragma unroll
    for (int i = 0; i < NINS; ++i) q[(NSEM + i) * HWP + p] = f2bf(o[i]);
}

// ---------------------------------------------------------------------------
// ONE fused kernel per CRF iteration: separable 13x13 blur (zero-pad) +
// bilateral (edge-clamp, weights from staged image) + compat/cross/softmax.
// Tile 32x8 / 256 threads. Channels in double-buffered groups of 2:
//   stage raw 44x20 window (serves BOTH blur h-pass and bilateral taps)
//   h-pass -> hb (LDS), sync, v-pass + bilateral in regs, sync.
// ---------------------------------------------------------------------------
#define TTW 32
#define TTH 8
#define RW  (TTW + 12)        // 44  raw window width  (blur halo 6)
#define RH  (TTH + 12)        // 20  raw window height
#define RN  (RW * RH)         // 880
#define GC  2                 // channels per group
#define NGRP (NCH / GC)       // 14
#define RGN (GC * RN)         // 1760
#define RSLOT ((RGN + 255) / 256)  // 7
#define HBW TTW               // 32
#define HBH (TTH + 12)        // 20
#define HBN (HBW * HBH)       // 640
#define BW  (TTW + 4)         // 36  image window (bilateral halo 2)
#define BH  (TTH + 4)         // 12
#define BN  (BW * BH)         // 432

template <bool OUTBF>
__global__ __launch_bounds__(256) void iter_kernel(const unsigned short* __restrict__ qin,
                                                   const float* __restrict__ img,
                                                   const float* __restrict__ semL,
                                                   const float* __restrict__ insL,
                                                   const float* __restrict__ sem_sw,
                                                   const float* __restrict__ sem_bw,
                                                   const float* __restrict__ sem_compat,
                                                   const float* __restrict__ ins_sw,
                                                   const float* __restrict__ ins_bw,
                                                   const int*   __restrict__ labels,
                                                   const float* __restrict__ cross_is,
                                                   const float* __restrict__ cross_si,
                                                   void* __restrict__ qout_v) {
    __shared__ float raw[2][RGN];        // 14080 B  (zero-padded q windows)
    __shared__ float hb[GC * HBN];       //  5120 B  (h-blurred)
    __shared__ float limg[3 * BN];       //  5184 B  (edge-clamped image)
    __shared__ float sC[NSEM * NSEM];
    __shared__ float sMis[NINS * NSEM];
    __shared__ float sMsi[NINS * NSEM];
    __shared__ float sws[NSEM], sbs[NSEM], swi[NINS], sbi[NINS];

    const int t  = threadIdx.x;
    const int tx = t & 31;
    const int ty = t >> 5;
    const int x0 = blockIdx.x * TTW;
    const int y0 = blockIdx.y * TTH;
    const int x  = x0 + tx;
    const int y  = y0 + ty;
    const int p  = y * WW + x;

    if (t < NSEM * NSEM) sC[t] = sem_compat[t];
    if (t < NINS * NSEM) {
        int i = t / NSEM, o = t - i * NSEM;
        sMis[t] = cross_is[labels[i] * NSEM + o];
        sMsi[t] = cross_si[labels[i] * NSEM + o];  // [o_ins*12 + i_sem]
    }
    if (t < NSEM) { sws[t] = sem_sw[t]; sbs[t] = sem_bw[t]; }
    if (t < NINS) { int l = labels[t]; swi[t] = ins_sw[l]; sbi[t] = ins_bw[l]; }

    float k[13]; gauss13(k);

    // raw-window staging offsets (zero outside image), reused for all groups.
    // roff includes the cc*HWP channel-within-group offset.
    int   roff[RSLOT];
    float rmask[RSLOT];
#pragma unroll
    for (int j = 0; j < RSLOT; ++j) {
        int idx = t + j * 256;
        if (idx < RGN) {
            int cc  = idx / RN;
            int rem = idx - cc * RN;
            int ly  = rem / RW, lx = rem - ly * RW;
            int gy  = y0 - 6 + ly, gx = x0 - 6 + lx;
            bool v  = (gy >= 0 && gy < HH && gx >= 0 && gx < WW);
            roff[j] = cc * HWP + (v ? gy * WW + gx : 0);
            rmask[j] = v ? 1.f : 0.f;
        } else { roff[j] = 0; rmask[j] = 0.f; }
    }

#define STAGE_Q(c0, dst)                                                     \
    _Pragma("unroll")                                                        \
    for (int j = 0; j < RSLOT; ++j) {                                        \
        int idx = t + j * 256;                                               \
        if (idx < RGN)                                                       \
            dst[idx] = bf2f(qin[(size_t)(c0) * HWP + roff[j]]) * rmask[j];   \
    }

    // stage image window (edge-clamped) + q group 0
    for (int idx = t; idx < 3 * BN; idx += 256) {
        int cc  = idx / BN;
        int rem = idx - cc * BN;
        int ly  = rem / BW, lx = rem - ly * BW;
        int gy  = min(max(y0 - 2 + ly, 0), HH - 1);
        int gx  = min(max(x0 - 2 + lx, 0), WW - 1);
        limg[idx] = img[(size_t)cc * HWP + gy * WW + gx];
    }
    STAGE_Q(0, raw[0])
    __syncthreads();

    // per-pixel bilateral weights from staged image window
    float wnr[25];
    {
        const int wc = (ty + 2) * BW + (tx + 2);
        float i0 = limg[wc], i1 = limg[BN + wc], i2 = limg[2 * BN + wc];
        float den = 0.f;
        int d = 0;
#pragma unroll
        for (int dy = 0; dy < 5; ++dy) {
#pragma unroll
            for (int dx = 0; dx < 5; ++dx) {
                int nb = (ty + dy) * BW + (tx + dx);
                float d0 = limg[nb] - i0;
                float d1 = limg[BN + nb] - i1;
                float d2 = limg[2 * BN + nb] - i2;
                float cd = d0 * d0 + d1 * d1 + d2 * d2;
                float sd = (float)((dy - 2) * (dy - 2) + (dx - 2) * (dx - 2));
                float wv = __expf(-sd * (1.f / 18.f) - cd * (1.f / 0.045f));
                wnr[d++] = wv; den += wv;
            }
        }
        float inv = 1.f / den;
#pragma unroll
        for (int j = 0; j < 25; ++j) wnr[j] *= inv;
    }

    // bilateral tap coords in the raw window (edge-clamped -> always in-window
    // and in-image, so the zero-padded window holds the true edge-pad values)
    int wyo[5], wxo[5];
#pragma unroll
    for (int d = 0; d < 5; ++d) {
        wyo[d] = (min(max(y + d - 2, 0), HH - 1) - y0 + 6) * RW;
        wxo[d] =  min(max(x + d - 2, 0), WW - 1) - x0 + 6;
    }

    // main channel loop: u[c] = w_sp[c]*blur(q_c)|p + w_bl[c]*bilateral(q_c)|p
    float u[NCH];
#pragma unroll
    for (int g = 0; g < NGRP; ++g) {
        const int b = g & 1;
        if (g + 1 < NGRP) { STAGE_Q((g + 1) * GC, raw[1 - b]) }  // prefetch

        // h-pass: GC x 20 x 32 positions
#pragma unroll
        for (int j = 0; j < (GC * HBN) / 256; ++j) {
            int idx = t + j * 256;
            int cc  = idx / HBN;
            int rem = idx - cc * HBN;
            int ly  = rem >> 5, lx = rem & 31;
            const float* r = &raw[b][cc * RN + ly * RW + lx];
            float acc = 0.f;
#pragma unroll
            for (int jj = 0; jj < 13; ++jj) acc = fmaf(k[jj], r[jj], acc);
            hb[idx] = acc;
        }
        __syncthreads();   // hb visible (also drains prefetch stores)

#pragma unroll
        for (int cc = 0; cc < GC; ++cc) {
            const int c = g * GC + cc;
            // v-pass at p
            float spv = 0.f;
            const float* hcol = &hb[cc * HBN + ty * HBW + tx];
#pragma unroll
            for (int jj = 0; jj < 13; ++jj) spv = fmaf(k[jj], hcol[jj * HBW], spv);
            // bilateral at p
            float blv = 0.f;
            const float* rb = &raw[b][cc * RN];
            int d = 0;
#pragma unroll
            for (int dy = 0; dy < 5; ++dy)
#pragma unroll
                for (int dx = 0; dx < 5; ++dx)
                    blv = fmaf(wnr[d++], rb[wyo[dy] + wxo[dx]], blv);
            float wsp = (c < NSEM) ? sws[c] : swi[c - NSEM];
            float wbl = (c < NSEM) ? sbs[c] : sbi[c - NSEM];
            u[c] = wsp * spv + wbl * blv;
        }
        __syncthreads();   // raw[b]/hb reads done before overwrite next iter
    }

    // pointwise tail (logits fp32)
    float ts[NSEM];
#pragma unroll
    for (int o = 0; o < NSEM; ++o) {
        float a = semL[o * HWP + p];
#pragma unroll
        for (int i = 0; i < NSEM; ++i) a = fmaf(sC[i * NSEM + o], u[i], a);
        ts[o] = a;
    }
    float ti[NINS];
#pragma unroll
    for (int i = 0; i < NINS; ++i)
        ti[i] = insL[i * HWP + p] + u[NSEM + i];

    float sIns[NINS], sSem[NSEM];
    softmaxN<NINS>(ti, sIns);
    softmaxN<NSEM>(ts, sSem);

    float nts[NSEM];
#pragma unroll
    for (int o = 0; o < NSEM; ++o) {
        float a = ts[o];
#pragma unroll
        for (int i = 0; i < NINS; ++i) a = fmaf(sMis[i * NSEM + o], sIns[i], a);
        nts[o] = a;
    }
    float nti[NINS];
#pragma unroll
    for (int o = 0; o < NINS; ++o) {
        float a = ti[o];
#pragma unroll
        for (int i = 0; i < NSEM; ++i) a = fmaf(sMsi[o * NSEM + i], sSem[i], a);
        nti[o] = a;
    }

    float oq[NINS];
    softmaxN<NSEM>(nts, oq);
#pragma unroll
    for (int i = 0; i < NSEM; ++i) {
        if (OUTBF) ((unsigned short*)qout_v)[i * HWP + p] = f2bf(oq[i]);
        else       ((float*)qout_v)[i * HWP + p] = oq[i];
    }
    softmaxN<NINS>(nti, oq);
#pragma unroll
    for (int i = 0; i < NINS; ++i) {
        if (OUTBF) ((unsigned short*)qout_v)[(NSEM + i) * HWP + p] = f2bf(oq[i]);
        else       ((float*)qout_v)[(NSEM + i) * HWP + p] = oq[i];
    }
#undef STAGE_Q
}

// ---------------------------------------------------------------------------
extern "C" void kernel_launch(void* const* d_in, const int* in_sizes, int n_in,
                              void* d_out, int out_size, void* d_ws, size_t ws_size,
                              hipStream_t stream) {
    const float* image      = (const float*)d_in[0];
    const float* semL       = (const float*)d_in[1];
    const float* insL       = (const float*)d_in[2];
    const int*   labels     = (const int*)  d_in[3];
    const float* sem_sw     = (const float*)d_in[4];
    const float* sem_bw     = (const float*)d_in[5];
    const float* sem_compat = (const float*)d_in[6];
    const float* ins_sw     = (const float*)d_in[7];
    const float* ins_bw     = (const float*)d_in[8];
    const float* cross_is   = (const float*)d_in[9];
    const float* cross_si   = (const float*)d_in[10];

    // Workspace (bf16 ushort): A[28HW] | B[28HW]
    unsigned short* ws = (unsigned short*)d_ws;
    unsigned short* A  = ws;
    unsigned short* B  = A + (size_t)NCH * HWP;

    const int PIX_BLOCKS = HWP / 256;  // 1200
    init_kernel<<<PIX_BLOCKS, 256, 0, stream>>>(semL, insL, A);

    dim3 tgrid(WW / TTW, HH / TTH);    // 20 x 60 = 1200 blocks

    iter_kernel<true><<<tgrid, 256, 0, stream>>>(A, image, semL, insL,
                                                 sem_sw, sem_bw, sem_compat,
                                                 ins_sw, ins_bw, labels,
                                                 cross_is, cross_si, (void*)B);
    iter_kernel<true><<<tgrid, 256, 0, stream>>>(B, image, semL, insL,
                                                 sem_sw, sem_bw, sem_compat,
                                                 ins_sw, ins_bw, labels,
                                                 cross_is, cross_si, (void*)A);
    iter_kernel<false><<<tgrid, 256, 0, stream>>>(A, image, semL, insL,
                                                  sem_sw, sem_bw, sem_compat,
                                                  ins_sw, ins_bw, labels,
                                                  cross_is, cross_si, d_out);
}

// Round 7
// 390.254 us; speedup vs baseline: 7.0295x; 7.0295x over previous
//
#include <hip/hip_runtime.h>

// Problem constants (fixed by reference)
#define HH   480
#define WW   640
#define HWP  (HH*WW)      // 307200
#define NSEM 12
#define NINS 16
#define NCH  28           // sem channels then ins channels

// ---------------------------------------------------------------------------
// bf16 helpers (raw ushort storage, RNE rounding)
// ---------------------------------------------------------------------------
__device__ __forceinline__ float bf2f(unsigned short u) {
    return __uint_as_float(((unsigned int)u) << 16);
}
__device__ __forceinline__ unsigned short f2bf(float f) {
    unsigned int b = __float_as_uint(f);
    return (unsigned short)((b + 0x7FFFu + ((b >> 16) & 1u)) >> 16);
}

// 13-tap Gaussian (sigma=3, r=6)
__device__ __forceinline__ void gauss13(float k[13]) {
    float s = 0.f;
#pragma unroll
    for (int j = 0; j < 13; ++j) {
        float xx = (float)(j - 6);
        float v  = __expf(-(xx * xx) * (1.f / 18.f));
        k[j] = v; s += v;
    }
    float inv = 1.f / s;
#pragma unroll
    for (int j = 0; j < 13; ++j) k[j] *= inv;
}

template <int N>
__device__ __forceinline__ void softmaxN(const float* __restrict__ in, float* __restrict__ out) {
    float m = in[0];
#pragma unroll
    for (int i = 1; i < N; ++i) m = fmaxf(m, in[i]);
    float s = 0.f;
#pragma unroll
    for (int i = 0; i < N; ++i) { float e = __expf(in[i] - m); out[i] = e; s += e; }
    float inv = 1.f / s;
#pragma unroll
    for (int i = 0; i < N; ++i) out[i] *= inv;
}

// ---------------------------------------------------------------------------
// Init: softmax(logits) -> q (bf16)
// ---------------------------------------------------------------------------
__global__ __launch_bounds__(256) void init_kernel(const float* __restrict__ semL,
                                                   const float* __restrict__ insL,
                                                   unsigned short* __restrict__ q) {
    int p = blockIdx.x * 256 + threadIdx.x;
    float v[NINS], o[NINS];
#pragma unroll
    for (int i = 0; i < NSEM; ++i) v[i] = semL[i * HWP + p];
    softmaxN<NSEM>(v, o);
#pragma unroll
    for (int i = 0; i < NSEM; ++i) q[i * HWP + p] = f2bf(o[i]);
#pragma unroll
    for (int i = 0; i < NINS; ++i) v[i] = insL[i * HWP + p];
    softmaxN<NINS>(v, o);
#pragma unroll
    for (int i = 0; i < NINS; ++i) q[(NSEM + i) * HWP + p] = f2bf(o[i]);
}

// ---------------------------------------------------------------------------
// Fused separable 13x13 blur (zero pad), LDS-tiled 64x32, bf16 in/out.
// (Round-2 structure, validated at ~55 us fp32; bf16 halves its streams.)
// ---------------------------------------------------------------------------
#define BTW 64
#define BTH 32
#define BR  6
__global__ __launch_bounds__(256) void blur_fused_kernel(const unsigned short* __restrict__ in,
                                                         unsigned short* __restrict__ out) {
    __shared__ float raw[(BTH + 2 * BR) * (BTW + 2 * BR)];  // 44*76 fp32
    __shared__ float hb[(BTH + 2 * BR) * BTW];              // 44*64 fp32
    const int t  = threadIdx.x;
    const int x0 = blockIdx.x * BTW;
    const int y0 = blockIdx.y * BTH;
    const int c  = blockIdx.z;
    const unsigned short* __restrict__ plane = in + (size_t)c * HWP;

    float k[13]; gauss13(k);

    const int RAWW = BTW + 2 * BR;            // 76
    const int RAWN = RAWW * (BTH + 2 * BR);   // 3344
    for (int idx = t; idx < RAWN; idx += 256) {
        int ly = idx / RAWW, lx = idx - ly * RAWW;
        int gy = y0 - BR + ly, gx = x0 - BR + lx;
        float v = 0.f;
        if (gy >= 0 && gy < HH && gx >= 0 && gx < WW) v = bf2f(plane[gy * WW + gx]);
        raw[idx] = v;
    }
    __syncthreads();

    const int HBN = BTW * (BTH + 2 * BR);     // 2816
    for (int idx = t; idx < HBN; idx += 256) {
        int ly = idx / BTW, lx = idx - ly * BTW;
        const float* r = raw + ly * RAWW + lx;
        float acc = 0.f;
#pragma unroll
        for (int j = 0; j < 13; ++j) acc = fmaf(k[j], r[j], acc);
        hb[idx] = acc;
    }
    __syncthreads();

    for (int idx = t; idx < BTW * BTH; idx += 256) {
        int ly = idx / BTW, lx = idx - ly * BTW;
        const float* hcol = hb + ly * BTW + lx;
        float acc = 0.f;
#pragma unroll
        for (int j = 0; j < 13; ++j) acc = fmaf(k[j], hcol[j * BTW], acc);
        out[(size_t)c * HWP + (y0 + ly) * WW + (x0 + lx)] = f2bf(acc);
    }
}

// ---------------------------------------------------------------------------
// Iteration tail (round-3 validated structure: DOUBLE-BUFFERED channel groups).
// 32x8 pixel tile / 256 threads (halo amp 1.69x). q/sp bf16, logits fp32.
// ---------------------------------------------------------------------------
#define TTW 32
#define TTH 8
#define GC  7
#define NG  (NCH / GC)        // 4
#define TWW (TTW + 4)         // 36
#define TWH (TTH + 4)         // 12
#define TWN (TWW * TWH)       // 432
#define GN  (GC * TWN)        // 3024
#define NSLOT ((GN + 255) / 256)  // 12

template <bool OUTBF>
__global__ __launch_bounds__(256) void tail_kernel(const unsigned short* __restrict__ qin,
                                                   const unsigned short* __restrict__ sp,
                                                   const float* __restrict__ img,
                                                   const float* __restrict__ semL,
                                                   const float* __restrict__ insL,
                                                   const float* __restrict__ sem_sw,
                                                   const float* __restrict__ sem_bw,
                                                   const float* __restrict__ sem_compat,
                                                   const float* __restrict__ ins_sw,
                                                   const float* __restrict__ ins_bw,
                                                   const int*   __restrict__ labels,
                                                   const float* __restrict__ cross_is,
                                                   const float* __restrict__ cross_si,
                                                   void* __restrict__ qout_v) {
    __shared__ float lq[2][GN];          // 2 x 12096 B
    __shared__ float limg[3 * TWN];      // 5184 B
    __shared__ float sC[NSEM * NSEM];
    __shared__ float sMis[NINS * NSEM];
    __shared__ float sMsi[NINS * NSEM];
    __shared__ float sws[NSEM], sbs[NSEM], swi[NINS], sbi[NINS];

    const int t  = threadIdx.x;
    const int tx = t & 31;
    const int ty = t >> 5;
    const int x0 = blockIdx.x * TTW;
    const int y0 = blockIdx.y * TTH;
    const int p  = (y0 + ty) * WW + (x0 + tx);

    if (t < NSEM * NSEM) sC[t] = sem_compat[t];
    if (t < NINS * NSEM) {
        int i = t / NSEM, o = t - i * NSEM;
        sMis[t] = cross_is[labels[i] * NSEM + o];
        sMsi[t] = cross_si[labels[i] * NSEM + o];  // [o_ins*12 + i_sem]
    }
    if (t < NSEM) { sws[t] = sem_sw[t]; sbs[t] = sem_bw[t]; }
    if (t < NINS) { int l = labels[t]; swi[t] = ins_sw[l]; sbi[t] = ins_bw[l]; }

    // staging offsets (identical clamped gy/gx for every channel group)
    int goff[NSLOT];
#pragma unroll
    for (int j = 0; j < NSLOT; ++j) {
        int idx = t + j * 256;
        if (idx < GN) {
            int cc  = idx / TWN;
            int rem = idx - cc * TWN;
            int ly  = rem / TWW, lx = rem - ly * TWW;
            int gy  = min(max(y0 - 2 + ly, 0), HH - 1);
            int gx  = min(max(x0 - 2 + lx, 0), WW - 1);
            goff[j] = cc * HWP + gy * WW + gx;
        } else goff[j] = 0;
    }

    // stage image window (fp32) + q group 0 into buffer 0
    for (int idx = t; idx < 3 * TWN; idx += 256) {
        int cc  = idx / TWN;
        int rem = idx - cc * TWN;
        int ly  = rem / TWW, lx = rem - ly * TWW;
        int gy  = min(max(y0 - 2 + ly, 0), HH - 1);
        int gx  = min(max(x0 - 2 + lx, 0), WW - 1);
        limg[idx] = img[(size_t)cc * HWP + gy * WW + gx];
    }
#pragma unroll
    for (int j = 0; j < NSLOT; ++j) {
        int idx = t + j * 256;
        if (idx < GN) lq[0][idx] = bf2f(qin[goff[j]]);
    }
    __syncthreads();

    // per-pixel bilateral weights from staged image window
    const int wc = (ty + 2) * TWW + (tx + 2);
    float i0 = limg[wc], i1 = limg[TWN + wc], i2 = limg[2 * TWN + wc];
    float wnr[25];
    {
        float den = 0.f;
        int d = 0;
#pragma unroll
        for (int dy = 0; dy < 5; ++dy) {
#pragma unroll
            for (int dx = 0; dx < 5; ++dx) {
                int nb = (ty + dy) * TWW + (tx + dx);
                float d0 = limg[nb] - i0;
                float d1 = limg[TWN + nb] - i1;
                float d2 = limg[2 * TWN + nb] - i2;
                float cd = d0 * d0 + d1 * d1 + d2 * d2;
                float sd = (float)((dy - 2) * (dy - 2) + (dx - 2) * (dx - 2));
                float wv = __expf(-sd * (1.f / 18.f) - cd * (1.f / 0.045f));
                wnr[d++] = wv; den += wv;
            }
        }
        float inv = 1.f / den;
#pragma unroll
        for (int j = 0; j < 25; ++j) wnr[j] *= inv;
    }

    // bilateral gather, double-buffered channel groups (prefetch overlaps compute)
    float bl[NCH];
#pragma unroll
    for (int c = 0; c < NCH; ++c) bl[c] = 0.f;

    for (int g = 0; g < NG; ++g) {
        if (g + 1 < NG) {
            const unsigned short* pl = qin + (size_t)(g + 1) * GC * HWP;
            float* dst = lq[(g + 1) & 1];
#pragma unroll
            for (int j = 0; j < NSLOT; ++j) {
                int idx = t + j * 256;
                if (idx < GN) dst[idx] = bf2f(pl[goff[j]]);
            }
        }
        const float* base = lq[g & 1];
        const int c0 = g * GC;
#pragma unroll
        for (int cc = 0; cc < GC; ++cc) {
            const float* w0 = base + cc * TWN + ty * TWW + tx;
            float a = 0.f;
            int d = 0;
#pragma unroll
            for (int dy = 0; dy < 5; ++dy)
#pragma unroll
                for (int dx = 0; dx < 5; ++dx)
                    a = fmaf(wnr[d++], w0[dy * TWW + dx], a);
            bl[c0 + cc] = a;
        }
        __syncthreads();  // prefetch visible; base reads done before overwrite
    }

    // pointwise tail (logits fp32)
    float comb[NSEM];
#pragma unroll
    for (int i = 0; i < NSEM; ++i)
        comb[i] = sws[i] * bf2f(sp[i * HWP + p]) + sbs[i] * bl[i];
    float ts[NSEM];
#pragma unroll
    for (int o = 0; o < NSEM; ++o) {
        float a = semL[o * HWP + p];
#pragma unroll
        for (int i = 0; i < NSEM; ++i) a = fmaf(sC[i * NSEM + o], comb[i], a);
        ts[o] = a;
    }

    float ti[NINS];
#pragma unroll
    for (int i = 0; i < NINS; ++i)
        ti[i] = insL[i * HWP + p] + swi[i] * bf2f(sp[(NSEM + i) * HWP + p]) + sbi[i] * bl[NSEM + i];

    float sIns[NINS], sSem[NSEM];
    softmaxN<NINS>(ti, sIns);
    softmaxN<NSEM>(ts, sSem);

    float nts[NSEM];
#pragma unroll
    for (int o = 0; o < NSEM; ++o) {
        float a = ts[o];
#pragma unroll
        for (int i = 0; i < NINS; ++i) a = fmaf(sMis[i * NSEM + o], sIns[i], a);
        nts[o] = a;
    }
    float nti[NINS];
#pragma unroll
    for (int o = 0; o < NINS; ++o) {
        float a = ti[o];
#pragma unroll
        for (int i = 0; i < NSEM; ++i) a = fmaf(sMsi[o * NSEM + i], sSem[i], a);
        nti[o] = a;
    }

    float oq[NINS];
    softmaxN<NSEM>(nts, oq);
#pragma unroll
    for (int i = 0; i < NSEM; ++i) {
        if (OUTBF) ((unsigned short*)qout_v)[i * HWP + p] = f2bf(oq[i]);
        else       ((float*)qout_v)[i * HWP + p] = oq[i];
    }
    softmaxN<NINS>(nti, oq);
#pragma unroll
    for (int i = 0; i < NINS; ++i) {
        if (OUTBF) ((unsigned short*)qout_v)[(NSEM + i) * HWP + p] = f2bf(oq[i]);
        else       ((float*)qout_v)[(NSEM + i) * HWP + p] = oq[i];
    }
}

// ---------------------------------------------------------------------------
extern "C" void kernel_launch(void* const* d_in, const int* in_sizes, int n_in,
                              void* d_out, int out_size, void* d_ws, size_t ws_size,
                              hipStream_t stream) {
    const float* image      = (const float*)d_in[0];
    const float* semL       = (const float*)d_in[1];
    const float* insL       = (const float*)d_in[2];
    const int*   labels     = (const int*)  d_in[3];
    const float* sem_sw     = (const float*)d_in[4];
    const float* sem_bw     = (const float*)d_in[5];
    const float* sem_compat = (const float*)d_in[6];
    const float* ins_sw     = (const float*)d_in[7];
    const float* ins_bw     = (const float*)d_in[8];
    const float* cross_is   = (const float*)d_in[9];
    const float* cross_si   = (const float*)d_in[10];

    // Workspace (bf16 ushort): A[28HW] | B[28HW] | S[28HW]
    unsigned short* ws = (unsigned short*)d_ws;
    unsigned short* A  = ws;
    unsigned short* B  = A + (size_t)NCH * HWP;
    unsigned short* S  = B + (size_t)NCH * HWP;

    const int PIX_BLOCKS = HWP / 256;  // 1200
    init_kernel<<<PIX_BLOCKS, 256, 0, stream>>>(semL, insL, A);

    dim3 bgrid(WW / BTW, HH / BTH, NCH);    // 10 x 15 x 28
    dim3 tgrid(WW / TTW, HH / TTH);         // 20 x 60

    unsigned short* qin[3] = { A, B, A };
    for (int it = 0; it < 3; ++it) {
        blur_fused_kernel<<<bgrid, 256, 0, stream>>>(qin[it], S);
        if (it < 2) {
            unsigned short* qo = (it == 0) ? B : A;
            tail_kernel<true><<<tgrid, 256, 0, stream>>>(qin[it], S, image, semL, insL,
                                                         sem_sw, sem_bw, sem_compat,
                                                         ins_sw, ins_bw, labels,
                                                         cross_is, cross_si, (void*)qo);
        } else {
            tail_kernel<false><<<tgrid, 256, 0, stream>>>(qin[it], S, image, semL, insL,
                                                          sem_sw, sem_bw, sem_compat,
                                                          ins_sw, ins_bw, labels,
                                                          cross_is, cross_si, d_out);
        }
    }
}

// Round 8
// 315.052 us; speedup vs baseline: 8.7075x; 1.2387x over previous
//
#include <hip/hip_runtime.h>

// Problem constants (fixed by reference)
#define HH   480
#define WW   640
#define HWP  (HH*WW)      // 307200
#define NSEM 12
#define NINS 16
#define NCH  28           // sem channels then ins channels

typedef _Float16 f16_t;

union P32 { f16_t h[32]; int4 v[4]; };      // one pixel's channels-last record
union I4H8 { int4 v; f16_t h[8]; };

// 13-tap Gaussian (sigma=3, r=6)
__device__ __forceinline__ void gauss13(float k[13]) {
    float s = 0.f;
#pragma unroll
    for (int j = 0; j < 13; ++j) {
        float xx = (float)(j - 6);
        float v  = __expf(-(xx * xx) * (1.f / 18.f));
        k[j] = v; s += v;
    }
    float inv = 1.f / s;
#pragma unroll
    for (int j = 0; j < 13; ++j) k[j] *= inv;
}

template <int N>
__device__ __forceinline__ void softmaxN(const float* __restrict__ in, float* __restrict__ out) {
    float m = in[0];
#pragma unroll
    for (int i = 1; i < N; ++i) m = fmaxf(m, in[i]);
    float s = 0.f;
#pragma unroll
    for (int i = 0; i < N; ++i) { float e = __expf(in[i] - m); out[i] = e; s += e; }
    float inv = 1.f / s;
#pragma unroll
    for (int i = 0; i < N; ++i) out[i] *= inv;
}

// ---------------------------------------------------------------------------
// Init: softmax(logits) -> qcl (channels-last f16, stride 32) + qpm (plane f16)
// ---------------------------------------------------------------------------
__global__ __launch_bounds__(256) void init_kernel(const float* __restrict__ semL,
                                                   const float* __restrict__ insL,
                                                   int4* __restrict__ qcl4,
                                                   f16_t* __restrict__ qpm) {
    int p = blockIdx.x * 256 + threadIdx.x;
    float v[NINS], o[NINS];
    P32 pk;
#pragma unroll
    for (int i = 0; i < 32; ++i) pk.h[i] = (f16_t)0.f;
#pragma unroll
    for (int i = 0; i < NSEM; ++i) v[i] = semL[i * HWP + p];
    softmaxN<NSEM>(v, o);
#pragma unroll
    for (int i = 0; i < NSEM; ++i) { f16_t h = (f16_t)o[i]; pk.h[i] = h; qpm[i * HWP + p] = h; }
#pragma unroll
    for (int i = 0; i < NINS; ++i) v[i] = insL[i * HWP + p];
    softmaxN<NINS>(v, o);
#pragma unroll
    for (int i = 0; i < NINS; ++i) { f16_t h = (f16_t)o[i]; pk.h[NSEM + i] = h; qpm[(NSEM + i) * HWP + p] = h; }
#pragma unroll
    for (int j = 0; j < 4; ++j) qcl4[p * 4 + j] = pk.v[j];
}

// ---------------------------------------------------------------------------
// Fused separable 13x13 blur (zero pad), LDS-tiled 64x32, f16 in/out.
// Halo-8 staging (16-B aligned both sides); sliding-register h/v passes.
// ---------------------------------------------------------------------------
#define BTW 64
#define BTH 32
#define RAWW 80                    // halo 8 left/right (>=6), 16-B aligned rows
#define RAWH 44                    // halo 6 top/bottom
__global__ __launch_bounds__(256) void blur_fused_kernel(const f16_t* __restrict__ in,
                                                         f16_t* __restrict__ out) {
    __shared__ float raw[RAWH * RAWW];   // 14080 B
    __shared__ float hb[RAWH * BTW];     // 11264 B
    const int t  = threadIdx.x;
    const int x0 = blockIdx.x * BTW;
    const int y0 = blockIdx.y * BTH;
    const int c  = blockIdx.z;
    const f16_t* __restrict__ plane = in + (size_t)c * HWP;

    float k[13]; gauss13(k);

    // stage: 44 rows x 10 groups of 8 px; groups are fully in- or out-of-bounds
    for (int idx = t; idx < RAWH * 10; idx += 256) {
        int row = idx / 10, g = idx - row * 10;
        int gy = y0 - 6 + row;
        int gx8 = x0 - 8 + g * 8;
        float4 lo = {0.f,0.f,0.f,0.f}, hi = {0.f,0.f,0.f,0.f};
        if (gy >= 0 && gy < HH && gx8 >= 0 && gx8 <= WW - 8) {
            I4H8 u; u.v = *(const int4*)&plane[gy * WW + gx8];
            lo.x = (float)u.h[0]; lo.y = (float)u.h[1]; lo.z = (float)u.h[2]; lo.w = (float)u.h[3];
            hi.x = (float)u.h[4]; hi.y = (float)u.h[5]; hi.z = (float)u.h[6]; hi.w = (float)u.h[7];
        }
        *(float4*)&raw[row * RAWW + g * 8]     = lo;
        *(float4*)&raw[row * RAWW + g * 8 + 4] = hi;
    }
    __syncthreads();

    // h-pass: 44 rows x 16 groups of 4 outputs; read 20 floats (5xb128)
    for (int idx = t; idx < RAWH * 16; idx += 256) {
        int row = idx >> 4, xg = idx & 15;
        const float* rp = &raw[row * RAWW + xg * 4];
        float f[20];
#pragma unroll
        for (int q4 = 0; q4 < 5; ++q4) {
            float4 v = *(const float4*)&rp[q4 * 4];
            f[q4*4+0]=v.x; f[q4*4+1]=v.y; f[q4*4+2]=v.z; f[q4*4+3]=v.w;
        }
        float4 o;
        float* op = &o.x;
#pragma unroll
        for (int j = 0; j < 4; ++j) {
            float a = 0.f;
#pragma unroll
            for (int i = 0; i < 13; ++i) a = fmaf(k[i], f[j + 2 + i], a);
            op[j] = a;
        }
        *(float4*)&hb[row * BTW + xg * 4] = o;
    }
    __syncthreads();

    // v-pass: 64 x 8 groups of 4 y-outputs; read 16 b32
    for (int idx = t; idx < BTW * 8; idx += 256) {
        int tx = idx & 63, yg = idx >> 6;
        float hh[16];
#pragma unroll
        for (int i = 0; i < 16; ++i) hh[i] = hb[(yg * 4 + i) * BTW + tx];
#pragma unroll
        for (int j = 0; j < 4; ++j) {
            float a = 0.f;
#pragma unroll
            for (int i = 0; i < 13; ++i) a = fmaf(k[i], hh[j + i], a);
            out[(size_t)c * HWP + (y0 + yg * 4 + j) * WW + (x0 + tx)] = (f16_t)a;
        }
    }
}

// ---------------------------------------------------------------------------
// Iteration tail. 32x8 tile / 256 threads. Channels-last f16 LDS (stride
// 5 int4 = 80 B to spread banks), single staging phase, b128 gather.
// ---------------------------------------------------------------------------
#define TTW 32
#define TTH 8
#define TWW (TTW + 4)         // 36
#define TWH (TTH + 4)         // 12
#define TWN (TWW * TWH)       // 432

template <bool LAST>
__global__ __launch_bounds__(256) void tail_kernel(const int4* __restrict__ qcl4,   // [HWP*4]
                                                   const f16_t* __restrict__ sp,
                                                   const float* __restrict__ img,
                                                   const float* __restrict__ semL,
                                                   const float* __restrict__ insL,
                                                   const float* __restrict__ sem_sw,
                                                   const float* __restrict__ sem_bw,
                                                   const float* __restrict__ sem_compat,
                                                   const float* __restrict__ ins_sw,
                                                   const float* __restrict__ ins_bw,
                                                   const int*   __restrict__ labels,
                                                   const float* __restrict__ cross_is,
                                                   const float* __restrict__ cross_si,
                                                   int4* __restrict__ qclo4,
                                                   f16_t* __restrict__ qpmo,
                                                   float* __restrict__ dout) {
    __shared__ int4  lq4[TWN * 5];       // 34560 B (slot 4 of 5 is pad)
    __shared__ float limg[3 * TWN];      // 5184 B
    __shared__ float sC[NSEM * NSEM];
    __shared__ float sMis[NINS * NSEM];
    __shared__ float sMsi[NINS * NSEM];
    __shared__ float sws[NSEM], sbs[NSEM], swi[NINS], sbi[NINS];

    const int t  = threadIdx.x;
    const int tx = t & 31;
    const int ty = t >> 5;
    const int x0 = blockIdx.x * TTW;
    const int y0 = blockIdx.y * TTH;
    const int p  = (y0 + ty) * WW + (x0 + tx);

    if (t < NSEM * NSEM) sC[t] = sem_compat[t];
    if (t < NINS * NSEM) {
        int i = t / NSEM, o = t - i * NSEM;
        sMis[t] = cross_is[labels[i] * NSEM + o];
        sMsi[t] = cross_si[labels[i] * NSEM + o];  // [o_ins*12 + i_sem]
    }
    if (t < NSEM) { sws[t] = sem_sw[t]; sbs[t] = sem_bw[t]; }
    if (t < NINS) { int l = labels[t]; swi[t] = ins_sw[l]; sbi[t] = ins_bw[l]; }

    // stage q window: 432 elems x 4 int4 groups = 1728 pure int4 copies
#pragma unroll
    for (int j = 0; j < 7; ++j) {
        int idx = t + j * 256;
        if (idx < TWN * 4) {
            int e = idx >> 2, grp = idx & 3;
            int ly = e / TWW, lx = e - ly * TWW;
            int gy = min(max(y0 - 2 + ly, 0), HH - 1);
            int gx = min(max(x0 - 2 + lx, 0), WW - 1);
            lq4[e * 5 + grp] = qcl4[(gy * WW + gx) * 4 + grp];
        }
    }
    // stage image window (fp32, edge-clamped)
    for (int idx = t; idx < 3 * TWN; idx += 256) {
        int cc  = idx / TWN;
        int rem = idx - cc * TWN;
        int ly  = rem / TWW, lx = rem - ly * TWW;
        int gy  = min(max(y0 - 2 + ly, 0), HH - 1);
        int gx  = min(max(x0 - 2 + lx, 0), WW - 1);
        limg[idx] = img[(size_t)cc * HWP + gy * WW + gx];
    }
    __syncthreads();

    // per-pixel bilateral weights from staged image window
    float wnr[25];
    {
        const int wc = (ty + 2) * TWW + (tx + 2);
        float i0 = limg[wc], i1 = limg[TWN + wc], i2 = limg[2 * TWN + wc];
        float den = 0.f;
        int d = 0;
#pragma unroll
        for (int dy = 0; dy < 5; ++dy) {
#pragma unroll
            for (int dx = 0; dx < 5; ++dx) {
                int nb = (ty + dy) * TWW + (tx + dx);
                float d0 = limg[nb] - i0;
                float d1 = limg[TWN + nb] - i1;
                float d2 = limg[2 * TWN + nb] - i2;
                float cd = d0 * d0 + d1 * d1 + d2 * d2;
                float sd = (float)((dy - 2) * (dy - 2) + (dx - 2) * (dx - 2));
                float wv = __expf(-sd * (1.f / 18.f) - cd * (1.f / 0.045f));
                wnr[d++] = wv; den += wv;
            }
        }
        float inv = 1.f / den;
#pragma unroll
        for (int j = 0; j < 25; ++j) wnr[j] *= inv;
    }

    // bilateral gather: 25 taps x 4 b128 (8 f16 channels each)
    float bl[NCH];
#pragma unroll
    for (int c = 0; c < NCH; ++c) bl[c] = 0.f;
#pragma unroll
    for (int dy = 0; dy < 5; ++dy) {
        int rb = ((ty + dy) * TWW + tx) * 5;
#pragma unroll
        for (int dx = 0; dx < 5; ++dx) {
            float w = wnr[dy * 5 + dx];
            int e5 = rb + dx * 5;
#pragma unroll
            for (int grp = 0; grp < 4; ++grp) {
                I4H8 u; u.v = lq4[e5 + grp];
                int lim = (grp == 3) ? 4 : 8;
#pragma unroll
                for (int i = 0; i < 8; ++i) {
                    if (i < lim)
                        bl[grp * 8 + i] = fmaf((float)u.h[i], w, bl[grp * 8 + i]);
                }
            }
        }
    }

    // pointwise tail (sp f16, logits fp32)
    float comb[NSEM];
#pragma unroll
    for (int i = 0; i < NSEM; ++i)
        comb[i] = sws[i] * (float)sp[i * HWP + p] + sbs[i] * bl[i];
    float ts[NSEM];
#pragma unroll
    for (int o = 0; o < NSEM; ++o) {
        float a = semL[o * HWP + p];
#pragma unroll
        for (int i = 0; i < NSEM; ++i) a = fmaf(sC[i * NSEM + o], comb[i], a);
        ts[o] = a;
    }
    float ti[NINS];
#pragma unroll
    for (int i = 0; i < NINS; ++i)
        ti[i] = insL[i * HWP + p] + swi[i] * (float)sp[(NSEM + i) * HWP + p] + sbi[i] * bl[NSEM + i];

    float sIns[NINS], sSem[NSEM];
    softmaxN<NINS>(ti, sIns);
    softmaxN<NSEM>(ts, sSem);

    float nts[NSEM];
#pragma unroll
    for (int o = 0; o < NSEM; ++o) {
        float a = ts[o];
#pragma unroll
        for (int i = 0; i < NINS; ++i) a = fmaf(sMis[i * NSEM + o], sIns[i], a);
        nts[o] = a;
    }
    float nti[NINS];
#pragma unroll
    for (int o = 0; o < NINS; ++o) {
        float a = ti[o];
#pragma unroll
        for (int i = 0; i < NSEM; ++i) a = fmaf(sMsi[o * NSEM + i], sSem[i], a);
        nti[o] = a;
    }

    float oq1[NSEM], oq2[NINS];
    softmaxN<NSEM>(nts, oq1);
    softmaxN<NINS>(nti, oq2);

    if (LAST) {
#pragma unroll
        for (int i = 0; i < NSEM; ++i) dout[i * HWP + p] = oq1[i];
#pragma unroll
        for (int i = 0; i < NINS; ++i) dout[(NSEM + i) * HWP + p] = oq2[i];
    } else {
        P32 pk;
#pragma unroll
        for (int i = 0; i < 32; ++i) pk.h[i] = (f16_t)0.f;
#pragma unroll
        for (int i = 0; i < NSEM; ++i) { f16_t h = (f16_t)oq1[i]; pk.h[i] = h; qpmo[i * HWP + p] = h; }
#pragma unroll
        for (int i = 0; i < NINS; ++i) { f16_t h = (f16_t)oq2[i]; pk.h[NSEM + i] = h; qpmo[(NSEM + i) * HWP + p] = h; }
#pragma unroll
        for (int j = 0; j < 4; ++j) qclo4[p * 4 + j] = pk.v[j];
    }
}

// ---------------------------------------------------------------------------
extern "C" void kernel_launch(void* const* d_in, const int* in_sizes, int n_in,
                              void* d_out, int out_size, void* d_ws, size_t ws_size,
                              hipStream_t stream) {
    const float* image      = (const float*)d_in[0];
    const float* semL       = (const float*)d_in[1];
    const float* insL       = (const float*)d_in[2];
    const int*   labels     = (const int*)  d_in[3];
    const float* sem_sw     = (const float*)d_in[4];
    const float* sem_bw     = (const float*)d_in[5];
    const float* sem_compat = (const float*)d_in[6];
    const float* ins_sw     = (const float*)d_in[7];
    const float* ins_bw     = (const float*)d_in[8];
    const float* cross_is   = (const float*)d_in[9];
    const float* cross_si   = (const float*)d_in[10];

    // Workspace: qclA[HWP*4 int4] | qclB | qpmA[28*HWP f16] | qpmB | sp[28*HWP f16]
    char* ws = (char*)d_ws;
    int4*  qclA = (int4*)ws;                                    ws += (size_t)HWP * 64;
    int4*  qclB = (int4*)ws;                                    ws += (size_t)HWP * 64;
    f16_t* qpmA = (f16_t*)ws;                                   ws += (size_t)NCH * HWP * 2;
    f16_t* qpmB = (f16_t*)ws;                                   ws += (size_t)NCH * HWP * 2;
    f16_t* sp   = (f16_t*)ws;

    const int PIX_BLOCKS = HWP / 256;  // 1200
    init_kernel<<<PIX_BLOCKS, 256, 0, stream>>>(semL, insL, qclA, qpmA);

    dim3 bgrid(WW / BTW, HH / BTH, NCH);    // 10 x 15 x 28
    dim3 tgrid(WW / TTW, HH / TTH);         // 20 x 60

    // iter 0: A -> B
    blur_fused_kernel<<<bgrid, 256, 0, stream>>>(qpmA, sp);
    tail_kernel<false><<<tgrid, 256, 0, stream>>>(qclA, sp, image, semL, insL,
                                                  sem_sw, sem_bw, sem_compat,
                                                  ins_sw, ins_bw, labels,
                                                  cross_is, cross_si, qclB, qpmB, nullptr);
    // iter 1: B -> A
    blur_fused_kernel<<<bgrid, 256, 0, stream>>>(qpmB, sp);
    tail_kernel<false><<<tgrid, 256, 0, stream>>>(qclB, sp, image, semL, insL,
                                                  sem_sw, sem_bw, sem_compat,
                                                  ins_sw, ins_bw, labels,
                                                  cross_is, cross_si, qclA, qpmA, nullptr);
    // iter 2: A -> d_out (fp32 plane-major)
    blur_fused_kernel<<<bgrid, 256, 0, stream>>>(qpmA, sp);
    tail_kernel<true><<<tgrid, 256, 0, stream>>>(qclA, sp, image, semL, insL,
                                                 sem_sw, sem_bw, sem_compat,
                                                 ins_sw, ins_bw, labels,
                                                 cross_is, cross_si, nullptr, nullptr, (float*)d_out);
}

// Round 9
// 280.566 us; speedup vs baseline: 9.7777x; 1.1229x over previous
//
#include <hip/hip_runtime.h>

// Problem constants (fixed by reference)
#define HH   480
#define WW   640
#define HWP  (HH*WW)      // 307200
#define NSEM 12
#define NINS 16
#define NCH  28           // sem channels then ins channels

typedef _Float16 f16_t;

union P32 { f16_t h[32]; int4 v[4]; };      // one pixel's channels-last record
union I4H8 { int4 v; f16_t h[8]; };
union I2H4 { int2 v; f16_t h[4]; };
union H4I2 { f16_t h[4]; int2 v; };

// 13-tap Gaussian (sigma=3, r=6)
__device__ __forceinline__ void gauss13(float k[13]) {
    float s = 0.f;
#pragma unroll
    for (int j = 0; j < 13; ++j) {
        float xx = (float)(j - 6);
        float v  = __expf(-(xx * xx) * (1.f / 18.f));
        k[j] = v; s += v;
    }
    float inv = 1.f / s;
#pragma unroll
    for (int j = 0; j < 13; ++j) k[j] *= inv;
}

template <int N>
__device__ __forceinline__ void softmaxN(const float* __restrict__ in, float* __restrict__ out) {
    float m = in[0];
#pragma unroll
    for (int i = 1; i < N; ++i) m = fmaxf(m, in[i]);
    float s = 0.f;
#pragma unroll
    for (int i = 0; i < N; ++i) { float e = __expf(in[i] - m); out[i] = e; s += e; }
    float inv = 1.f / s;
#pragma unroll
    for (int i = 0; i < N; ++i) out[i] *= inv;
}

// ---------------------------------------------------------------------------
// Init: softmax(logits) -> qcl (channels-last f16) + qpm (plane f16),
// plus f16 copies of the logits (8x finer ulp than bf16 -> ~+3e-3 error only)
// ---------------------------------------------------------------------------
__global__ __launch_bounds__(256) void init_kernel(const float* __restrict__ semL,
                                                   const float* __restrict__ insL,
                                                   int4* __restrict__ qcl4,
                                                   f16_t* __restrict__ qpm,
                                                   f16_t* __restrict__ semLh,
                                                   f16_t* __restrict__ insLh) {
    int p = blockIdx.x * 256 + threadIdx.x;
    float v[NINS], o[NINS];
    P32 pk;
#pragma unroll
    for (int i = 0; i < 32; ++i) pk.h[i] = (f16_t)0.f;
#pragma unroll
    for (int i = 0; i < NSEM; ++i) { v[i] = semL[i * HWP + p]; semLh[i * HWP + p] = (f16_t)v[i]; }
    softmaxN<NSEM>(v, o);
#pragma unroll
    for (int i = 0; i < NSEM; ++i) { f16_t h = (f16_t)o[i]; pk.h[i] = h; qpm[i * HWP + p] = h; }
#pragma unroll
    for (int i = 0; i < NINS; ++i) { v[i] = insL[i * HWP + p]; insLh[i * HWP + p] = (f16_t)v[i]; }
    softmaxN<NINS>(v, o);
#pragma unroll
    for (int i = 0; i < NINS; ++i) { f16_t h = (f16_t)o[i]; pk.h[NSEM + i] = h; qpm[(NSEM + i) * HWP + p] = h; }
#pragma unroll
    for (int j = 0; j < 4; ++j) qcl4[p * 4 + j] = pk.v[j];
}

// ---------------------------------------------------------------------------
// Fused separable 13x13 blur (zero pad), LDS-tiled 64x32, f16 in/out.
// ---------------------------------------------------------------------------
#define BTW 64
#define BTH 32
#define RAWW 80                    // halo 8 left/right, 16-B aligned rows
#define RAWH 44                    // halo 6 top/bottom
__global__ __launch_bounds__(256) void blur_fused_kernel(const f16_t* __restrict__ in,
                                                         f16_t* __restrict__ out) {
    __shared__ float raw[RAWH * RAWW];   // 14080 B
    __shared__ float hb[RAWH * BTW];     // 11264 B
    const int t  = threadIdx.x;
    const int x0 = blockIdx.x * BTW;
    const int y0 = blockIdx.y * BTH;
    const int c  = blockIdx.z;
    const f16_t* __restrict__ plane = in + (size_t)c * HWP;

    float k[13]; gauss13(k);

    // stage: 44 rows x 10 groups of 8 px; groups fully in- or out-of-bounds
    for (int idx = t; idx < RAWH * 10; idx += 256) {
        int row = idx / 10, g = idx - row * 10;
        int gy = y0 - 6 + row;
        int gx8 = x0 - 8 + g * 8;
        float4 lo = {0.f,0.f,0.f,0.f}, hi = {0.f,0.f,0.f,0.f};
        if (gy >= 0 && gy < HH && gx8 >= 0 && gx8 <= WW - 8) {
            I4H8 u; u.v = *(const int4*)&plane[gy * WW + gx8];
            lo.x = (float)u.h[0]; lo.y = (float)u.h[1]; lo.z = (float)u.h[2]; lo.w = (float)u.h[3];
            hi.x = (float)u.h[4]; hi.y = (float)u.h[5]; hi.z = (float)u.h[6]; hi.w = (float)u.h[7];
        }
        *(float4*)&raw[row * RAWW + g * 8]     = lo;
        *(float4*)&raw[row * RAWW + g * 8 + 4] = hi;
    }
    __syncthreads();

    // h-pass: 44 rows x 16 groups of 4 outputs; read 20 floats (5xb128)
    for (int idx = t; idx < RAWH * 16; idx += 256) {
        int row = idx >> 4, xg = idx & 15;
        const float* rp = &raw[row * RAWW + xg * 4];
        float f[20];
#pragma unroll
        for (int q4 = 0; q4 < 5; ++q4) {
            float4 v = *(const float4*)&rp[q4 * 4];
            f[q4*4+0]=v.x; f[q4*4+1]=v.y; f[q4*4+2]=v.z; f[q4*4+3]=v.w;
        }
        float4 o;
        float* op = &o.x;
#pragma unroll
        for (int j = 0; j < 4; ++j) {
            float a = 0.f;
#pragma unroll
            for (int i = 0; i < 13; ++i) a = fmaf(k[i], f[j + 2 + i], a);
            op[j] = a;
        }
        *(float4*)&hb[row * BTW + xg * 4] = o;
    }
    __syncthreads();

    // v-pass: each thread does 4 cols x 2 rows; 14 b128 reads, 2 dwordx2 stores
    {
        const int xg = t & 15;          // 16 col-groups of 4
        const int yg = t >> 4;          // 16 row-groups of 2
        float4 r[14];
#pragma unroll
        for (int i = 0; i < 14; ++i)
            r[i] = *(const float4*)&hb[(yg * 2 + i) * BTW + xg * 4];
#pragma unroll
        for (int j = 0; j < 2; ++j) {
            float a0 = 0.f, a1 = 0.f, a2 = 0.f, a3 = 0.f;
#pragma unroll
            for (int i = 0; i < 13; ++i) {
                float4 v = r[j + i];
                a0 = fmaf(k[i], v.x, a0); a1 = fmaf(k[i], v.y, a1);
                a2 = fmaf(k[i], v.z, a2); a3 = fmaf(k[i], v.w, a3);
            }
            H4I2 s;
            s.h[0] = (f16_t)a0; s.h[1] = (f16_t)a1; s.h[2] = (f16_t)a2; s.h[3] = (f16_t)a3;
            *(int2*)&out[(size_t)c * HWP + (y0 + yg * 2 + j) * WW + (x0 + xg * 4)] = s.v;
        }
    }
}

// ---------------------------------------------------------------------------
// Iteration tail. 32x8 tile / 256 threads. Channels-last f16 LDS:
//   lqA: 24 ch as 3x int4 (48-B stride, bank rotation period 8)
//   lqB:  4 ch as int2   ( 8-B stride)
// LDS ~31 KB -> 5 blocks/CU (was 3). f16 logits. 25 taps x (3 b128 + 1 b64).
// ---------------------------------------------------------------------------
#define TTW 32
#define TTH 8
#define TWW (TTW + 4)         // 36
#define TWH (TTH + 4)         // 12
#define TWN (TWW * TWH)       // 432

template <bool LAST>
__global__ __launch_bounds__(256, 5) void tail_kernel(const int4* __restrict__ qcl4,
                                                      const f16_t* __restrict__ sp,
                                                      const float* __restrict__ img,
                                                      const f16_t* __restrict__ semLh,
                                                      const f16_t* __restrict__ insLh,
                                                      const float* __restrict__ sem_sw,
                                                      const float* __restrict__ sem_bw,
                                                      const float* __restrict__ sem_compat,
                                                      const float* __restrict__ ins_sw,
                                                      const float* __restrict__ ins_bw,
                                                      const int*   __restrict__ labels,
                                                      const float* __restrict__ cross_is,
                                                      const float* __restrict__ cross_si,
                                                      int4* __restrict__ qclo4,
                                                      f16_t* __restrict__ qpmo,
                                                      float* __restrict__ dout) {
    __shared__ int4  lqA[TWN * 3];       // 20736 B (channels 0..23)
    __shared__ int2  lqB[TWN];           //  3456 B (channels 24..27)
    __shared__ float limg[3 * TWN];      //  5184 B
    __shared__ float sC[NSEM * NSEM];
    __shared__ float sMis[NINS * NSEM];
    __shared__ float sMsi[NINS * NSEM];
    __shared__ float sws[NSEM], sbs[NSEM], swi[NINS], sbi[NINS];

    const int t  = threadIdx.x;
    const int tx = t & 31;
    const int ty = t >> 5;
    const int x0 = blockIdx.x * TTW;
    const int y0 = blockIdx.y * TTH;
    const int p  = (y0 + ty) * WW + (x0 + tx);

    if (t < NSEM * NSEM) sC[t] = sem_compat[t];
    if (t < NINS * NSEM) {
        int i = t / NSEM, o = t - i * NSEM;
        sMis[t] = cross_is[labels[i] * NSEM + o];
        sMsi[t] = cross_si[labels[i] * NSEM + o];  // [o_ins*12 + i_sem]
    }
    if (t < NSEM) { sws[t] = sem_sw[t]; sbs[t] = sem_bw[t]; }
    if (t < NINS) { int l = labels[t]; swi[t] = ins_sw[l]; sbi[t] = ins_bw[l]; }

    // stage q window, A-part: idx = e*3+s  (TWN*3 = 1296)
#pragma unroll
    for (int j = 0; j < 6; ++j) {
        int idx = t + j * 256;
        if (idx < TWN * 3) {
            int e = idx / 3, s = idx - e * 3;
            int ly = e / TWW, lx = e - ly * TWW;
            int gy = min(max(y0 - 2 + ly, 0), HH - 1);
            int gx = min(max(x0 - 2 + lx, 0), WW - 1);
            lqA[idx] = qcl4[(gy * WW + gx) * 4 + s];
        }
    }
    // B-part: channels 24..27 = int2 #6 of the 64-B record
#pragma unroll
    for (int j = 0; j < 2; ++j) {
        int e = t + j * 256;
        if (e < TWN) {
            int ly = e / TWW, lx = e - ly * TWW;
            int gy = min(max(y0 - 2 + ly, 0), HH - 1);
            int gx = min(max(x0 - 2 + lx, 0), WW - 1);
            lqB[e] = ((const int2*)qcl4)[(gy * WW + gx) * 8 + 6];
        }
    }
    // image window (fp32, edge-clamped)
    for (int idx = t; idx < 3 * TWN; idx += 256) {
        int cc  = idx / TWN;
        int rem = idx - cc * TWN;
        int ly  = rem / TWW, lx = rem - ly * TWW;
        int gy  = min(max(y0 - 2 + ly, 0), HH - 1);
        int gx  = min(max(x0 - 2 + lx, 0), WW - 1);
        limg[idx] = img[(size_t)cc * HWP + gy * WW + gx];
    }
    __syncthreads();

    // per-pixel bilateral weights from staged image window
    float wnr[25];
    {
        const int wc = (ty + 2) * TWW + (tx + 2);
        float i0 = limg[wc], i1 = limg[TWN + wc], i2 = limg[2 * TWN + wc];
        float den = 0.f;
        int d = 0;
#pragma unroll
        for (int dy = 0; dy < 5; ++dy) {
#pragma unroll
            for (int dx = 0; dx < 5; ++dx) {
                int nb = (ty + dy) * TWW + (tx + dx);
                float d0 = limg[nb] - i0;
                float d1 = limg[TWN + nb] - i1;
                float d2 = limg[2 * TWN + nb] - i2;
                float cd = d0 * d0 + d1 * d1 + d2 * d2;
                float sd = (float)((dy - 2) * (dy - 2) + (dx - 2) * (dx - 2));
                float wv = __expf(-sd * (1.f / 18.f) - cd * (1.f / 0.045f));
                wnr[d++] = wv; den += wv;
            }
        }
        float inv = 1.f / den;
#pragma unroll
        for (int j = 0; j < 25; ++j) wnr[j] *= inv;
    }

    // bilateral gather: 25 taps x (3 b128 + 1 b64)
    float bl[NCH];
#pragma unroll
    for (int c = 0; c < NCH; ++c) bl[c] = 0.f;
#pragma unroll
    for (int dy = 0; dy < 5; ++dy) {
        int rb = (ty + dy) * TWW + tx;
#pragma unroll
        for (int dx = 0; dx < 5; ++dx) {
            float w = wnr[dy * 5 + dx];
            int e = rb + dx;
#pragma unroll
            for (int s = 0; s < 3; ++s) {
                I4H8 u; u.v = lqA[e * 3 + s];
#pragma unroll
                for (int i = 0; i < 8; ++i)
                    bl[s * 8 + i] = fmaf((float)u.h[i], w, bl[s * 8 + i]);
            }
            I2H4 ub; ub.v = lqB[e];
#pragma unroll
            for (int i = 0; i < 4; ++i)
                bl[24 + i] = fmaf((float)ub.h[i], w, bl[24 + i]);
        }
    }

    // pointwise tail (sp f16, logits f16)
    float comb[NSEM];
#pragma unroll
    for (int i = 0; i < NSEM; ++i)
        comb[i] = sws[i] * (float)sp[i * HWP + p] + sbs[i] * bl[i];
    float ts[NSEM];
#pragma unroll
    for (int o = 0; o < NSEM; ++o) {
        float a = (float)semLh[o * HWP + p];
#pragma unroll
        for (int i = 0; i < NSEM; ++i) a = fmaf(sC[i * NSEM + o], comb[i], a);
        ts[o] = a;
    }
    float ti[NINS];
#pragma unroll
    for (int i = 0; i < NINS; ++i)
        ti[i] = (float)insLh[i * HWP + p] + swi[i] * (float)sp[(NSEM + i) * HWP + p] + sbi[i] * bl[NSEM + i];

    float sIns[NINS], sSem[NSEM];
    softmaxN<NINS>(ti, sIns);
    softmaxN<NSEM>(ts, sSem);

    float nts[NSEM];
#pragma unroll
    for (int o = 0; o < NSEM; ++o) {
        float a = ts[o];
#pragma unroll
        for (int i = 0; i < NINS; ++i) a = fmaf(sMis[i * NSEM + o], sIns[i], a);
        nts[o] = a;
    }
    float nti[NINS];
#pragma unroll
    for (int o = 0; o < NINS; ++o) {
        float a = ti[o];
#pragma unroll
        for (int i = 0; i < NSEM; ++i) a = fmaf(sMsi[o * NSEM + i], sSem[i], a);
        nti[o] = a;
    }

    float oq1[NSEM], oq2[NINS];
    softmaxN<NSEM>(nts, oq1);
    softmaxN<NINS>(nti, oq2);

    if (LAST) {
#pragma unroll
        for (int i = 0; i < NSEM; ++i) dout[i * HWP + p] = oq1[i];
#pragma unroll
        for (int i = 0; i < NINS; ++i) dout[(NSEM + i) * HWP + p] = oq2[i];
    } else {
        P32 pk;
#pragma unroll
        for (int i = 0; i < 32; ++i) pk.h[i] = (f16_t)0.f;
#pragma unroll
        for (int i = 0; i < NSEM; ++i) { f16_t h = (f16_t)oq1[i]; pk.h[i] = h; qpmo[i * HWP + p] = h; }
#pragma unroll
        for (int i = 0; i < NINS; ++i) { f16_t h = (f16_t)oq2[i]; pk.h[NSEM + i] = h; qpmo[(NSEM + i) * HWP + p] = h; }
#pragma unroll
        for (int j = 0; j < 4; ++j) qclo4[p * 4 + j] = pk.v[j];
    }
}

// ---------------------------------------------------------------------------
extern "C" void kernel_launch(void* const* d_in, const int* in_sizes, int n_in,
                              void* d_out, int out_size, void* d_ws, size_t ws_size,
                              hipStream_t stream) {
    const float* image      = (const float*)d_in[0];
    const float* semL       = (const float*)d_in[1];
    const float* insL       = (const float*)d_in[2];
    const int*   labels     = (const int*)  d_in[3];
    const float* sem_sw     = (const float*)d_in[4];
    const float* sem_bw     = (const float*)d_in[5];
    const float* sem_compat = (const float*)d_in[6];
    const float* ins_sw     = (const float*)d_in[7];
    const float* ins_bw     = (const float*)d_in[8];
    const float* cross_is   = (const float*)d_in[9];
    const float* cross_si   = (const float*)d_in[10];

    // Workspace: qclA | qclB | qpmA | qpmB | sp | semLh | insLh
    char* ws = (char*)d_ws;
    int4*  qclA  = (int4*)ws;                                   ws += (size_t)HWP * 64;
    int4*  qclB  = (int4*)ws;                                   ws += (size_t)HWP * 64;
    f16_t* qpmA  = (f16_t*)ws;                                  ws += (size_t)NCH * HWP * 2;
    f16_t* qpmB  = (f16_t*)ws;                                  ws += (size_t)NCH * HWP * 2;
    f16_t* sp    = (f16_t*)ws;                                  ws += (size_t)NCH * HWP * 2;
    f16_t* semLh = (f16_t*)ws;                                  ws += (size_t)NSEM * HWP * 2;
    f16_t* insLh = (f16_t*)ws;

    const int PIX_BLOCKS = HWP / 256;  // 1200
    init_kernel<<<PIX_BLOCKS, 256, 0, stream>>>(semL, insL, qclA, qpmA, semLh, insLh);

    dim3 bgrid(WW / BTW, HH / BTH, NCH);    // 10 x 15 x 28
    dim3 tgrid(WW / TTW, HH / TTH);         // 20 x 60

    // iter 0: A -> B
    blur_fused_kernel<<<bgrid, 256, 0, stream>>>(qpmA, sp);
    tail_kernel<false><<<tgrid, 256, 0, stream>>>(qclA, sp, image, semLh, insLh,
                                                  sem_sw, sem_bw, sem_compat,
                                                  ins_sw, ins_bw, labels,
                                                  cross_is, cross_si, qclB, qpmB, nullptr);
    // iter 1: B -> A
    blur_fused_kernel<<<bgrid, 256, 0, stream>>>(qpmB, sp);
    tail_kernel<false><<<tgrid, 256, 0, stream>>>(qclB, sp, image, semLh, insLh,
                                                  sem_sw, sem_bw, sem_compat,
                                                  ins_sw, ins_bw, labels,
                                                  cross_is, cross_si, qclA, qpmA, nullptr);
    // iter 2: A -> d_out (fp32 plane-major)
    blur_fused_kernel<<<bgrid, 256, 0, stream>>>(qpmA, sp);
    tail_kernel<true><<<tgrid, 256, 0, stream>>>(qclA, sp, image, semLh, insLh,
                                                 sem_sw, sem_bw, sem_compat,
                                                 ins_sw, ins_bw, labels,
                                                 cross_is, cross_si, nullptr, nullptr, (float*)d_out);
}